// Round 10
// baseline (188.713 us; speedup 1.0000x reference)
//
#include <hip/hip_runtime.h>
#include <hip/hip_bf16.h>

#define D_MSA 384
#define NHEAD 12
#define DHID  32
#define BB    2
#define NN    256
#define LL    384
#define NBL   (BB * LL)          // 768 (b,l) pairs
#define WFROW (NHEAD * D_MSA)    // 4608

// ---- workspace layout (in floats) ----
#define WF_OFF 0
#define WF_SZ  ((size_t)NBL * WFROW)       // 3,538,944
#define CB_OFF (WF_OFF + WF_SZ)
#define CB_SZ  ((size_t)NBL * NHEAD)       // 9,216
#define LOG_OFF (CB_OFF + CB_SZ)
#define LOG_SZ ((size_t)NBL * NHEAD * NN)  // 2,359,296
#define WS_FLOATS (LOG_OFF + LOG_SZ)
#define WS_BYTES  (WS_FLOATS * 4)

// =====================================================================
// A (merged A1+A2): per 4 bl-rows: tar -> q (LDS) -> wf, cb.
// 192 blocks x 4 bl-rows, 256 thr.
// q phase: proven 16-lane-coalesced Wq reads + 4-stage shfl reduce.
// wf phase: proven thread-per-c column-coalesced Wk reads, q broadcast
// from LDS. No q_ws round trip, one less kernel boundary.
// =====================================================================
__global__ __launch_bounds__(256)
void seqw_a(const float* __restrict__ msa, const float* __restrict__ Wq,
            const float* __restrict__ bq, const float* __restrict__ Wk,
            const float* __restrict__ bk,
            float* __restrict__ wf_ws, float* __restrict__ cb_ws)
{
  __shared__ float tar[4][D_MSA];
  __shared__ float qs[4][D_MSA];
  const int t    = threadIdx.x;
  const int lane = t & 63;
  const int wv   = t >> 6;        // 0..3
  const int rowi = lane >> 4;     // 0..3
  const int seg  = lane & 15;     // 0..15
  const int bl0  = blockIdx.x * 4;
  const int b    = bl0 / LL, l0 = bl0 % LL;  // 4 | 384, never straddles b
  const float scale = 0.17677669529663687f;  // 1/sqrt(32)

  // tar rows contiguous: msa[b][0][l0..l0+3][:] = 384 float4
  const float* base = msa + ((size_t)b * NN * LL + l0) * D_MSA;
  for (int i = t; i < 4 * D_MSA / 4; i += 256)
    ((float4*)tar)[i] = ((const float4*)base)[i];
  __syncthreads();

  // ---- q[r][c] = scale*(tar[r] . Wq[c,:] + bq[c]) ----
#pragma unroll 1
  for (int cc = 0; cc < 24; ++cc) {
    const int c = wv * 96 + cc * 4 + rowi;
    const float* wr = Wq + (size_t)c * D_MSA + seg * 4;
    float a[4];
#pragma unroll
    for (int r = 0; r < 4; ++r) a[r] = 0.f;
#pragma unroll
    for (int j = 0; j < 6; ++j) {
      float4 w4 = *(const float4*)(wr + 64 * j);
#pragma unroll
      for (int r = 0; r < 4; ++r) {
        float4 tv = *(const float4*)&tar[r][64 * j + seg * 4];  // broadcast
        a[r] = fmaf(w4.x, tv.x, a[r]); a[r] = fmaf(w4.y, tv.y, a[r]);
        a[r] = fmaf(w4.z, tv.z, a[r]); a[r] = fmaf(w4.w, tv.w, a[r]);
      }
    }
#pragma unroll
    for (int m = 8; m; m >>= 1) {
#pragma unroll
      for (int r = 0; r < 4; ++r) a[r] += __shfl_xor(a[r], m);
    }
    if (seg == 0) {
      const float bqc = bq[c];
#pragma unroll
      for (int r = 0; r < 4; ++r) qs[r][c] = scale * (a[r] + bqc);
    }
  }
  __syncthreads();

  // ---- cb[r][h] = q_r,h . bk_h ----
  if (t < 4 * NHEAD) {
    const int r = t / NHEAD, h = t % NHEAD;
    float s = 0.f;
#pragma unroll
    for (int d = 0; d < DHID; ++d)
      s = fmaf(qs[r][h * DHID + d], bk[h * DHID + d], s);
    cb_ws[(size_t)(bl0 + r) * NHEAD + h] = s;
  }

  // ---- wf[r][h][c] = sum_d q[r][h*32+d] * Wk[h*32+d][c] ----
#pragma unroll 1
  for (int pass = 0; pass < 2; ++pass) {
    const int c = pass * 256 + t;
    if (c < D_MSA) {
#pragma unroll 1
      for (int h = 0; h < NHEAD; ++h) {
        float acc4[4];
#pragma unroll
        for (int r = 0; r < 4; ++r) acc4[r] = 0.f;
        const float* wkb = Wk + (size_t)(h * DHID) * D_MSA + c;
#pragma unroll 4
        for (int d = 0; d < DHID; ++d) {
          const float w = wkb[(size_t)d * D_MSA];
#pragma unroll
          for (int r = 0; r < 4; ++r)
            acc4[r] = fmaf(qs[r][h * DHID + d], w, acc4[r]);  // LDS broadcast
        }
#pragma unroll
        for (int r = 0; r < 4; ++r)
          wf_ws[(size_t)(bl0 + r) * WFROW + h * D_MSA + c] = acc4[r];
      }
    }
  }
}

// =====================================================================
// B: logits only. Grid 1536 = (bl, nhalf); 256 thr = 4 waves.
// XCD-chunked swizzle: same-bl pair + adjacent-l blocks share one XCD L2
// (wf slice fetched once per XCD; msa boundary lines stay local).
// Wave wv owns heads {3wv..3wv+2} and all 128 rows. Lanes = 8 rowi x 8
// seg; per LD instr 8-lane groups read 128B contiguous. G=8 rows per w4
// read (conflict-free broadcast). acc[8][3]=24 regs. 3-stage shfl reduce.
// NO min-occupancy launch_bounds (spill trap, rounds 2/5/6).
// =====================================================================
struct SmemB {
  float wf[NHEAD][D_MSA];   // 18 KB
  float cb[NHEAD];
  float attn[NHEAD][128];   // 6 KB
};

__global__ __launch_bounds__(256)
void seqw_b(const float* __restrict__ msa, const float* __restrict__ wf_ws,
            const float* __restrict__ cb_ws, float* __restrict__ log_ws)
{
  __shared__ SmemB sm;
  const int t    = threadIdx.x;
  const int lane = t & 63;
  const int wv   = t >> 6;        // 0..3
  const int rowi = lane >> 3;     // 0..7
  const int seg  = lane & 7;      // 0..7
  // chunked XCD swizzle: dispatch i (XCD = i%8) -> contiguous 192-chunk
  const int i0   = blockIdx.x;
  const int bid  = (i0 & 7) * (NBL * 2 / 8) + (i0 >> 3);
  const int bl   = bid >> 1;
  const int nblk = bid & 1;       // which 128-row half
  const int b    = bl / LL;
  const int l    = bl - b * LL;
  const int h0   = 3 * wv;

  // stage wf slice + cb
  {
    const float4* src = (const float4*)(wf_ws + (size_t)bl * WFROW);
    for (int i = t; i < WFROW / 4; i += 256) ((float4*)sm.wf)[i] = src[i];
    if (t < NHEAD) sm.cb[t] = cb_ws[(size_t)bl * NHEAD + t];
  }
  __syncthreads();

  const size_t rstride = (size_t)LL * D_MSA;
  const float* lanebase =
      msa + ((size_t)(b * NN + nblk * 128 + rowi) * LL + l) * D_MSA + seg * 4;

#define LDB(buf, ch, j)                                                         \
  {                                                                             \
    _Pragma("unroll")                                                           \
    for (int g = 0; g < 8; ++g)                                                 \
      buf[g] = *(const float4*)(lanebase +                                      \
                 (size_t)((ch) * 64 + g * 8) * rstride + 32 * (j));             \
  }
#define CPB(buf, j)                                                             \
  {                                                                             \
    float4 w0 = *(const float4*)&sm.wf[h0 + 0][32 * (j) + 4 * seg];             \
    float4 w1 = *(const float4*)&sm.wf[h0 + 1][32 * (j) + 4 * seg];             \
    float4 w2 = *(const float4*)&sm.wf[h0 + 2][32 * (j) + 4 * seg];             \
    _Pragma("unroll")                                                           \
    for (int g = 0; g < 8; ++g) {                                               \
      acc[g][0] = fmaf(buf[g].x, w0.x, acc[g][0]);                              \
      acc[g][0] = fmaf(buf[g].y, w0.y, acc[g][0]);                              \
      acc[g][0] = fmaf(buf[g].z, w0.z, acc[g][0]);                              \
      acc[g][0] = fmaf(buf[g].w, w0.w, acc[g][0]);                              \
      acc[g][1] = fmaf(buf[g].x, w1.x, acc[g][1]);                              \
      acc[g][1] = fmaf(buf[g].y, w1.y, acc[g][1]);                              \
      acc[g][1] = fmaf(buf[g].z, w1.z, acc[g][1]);                              \
      acc[g][1] = fmaf(buf[g].w, w1.w, acc[g][1]);                              \
      acc[g][2] = fmaf(buf[g].x, w2.x, acc[g][2]);                              \
      acc[g][2] = fmaf(buf[g].y, w2.y, acc[g][2]);                              \
      acc[g][2] = fmaf(buf[g].z, w2.z, acc[g][2]);                              \
      acc[g][2] = fmaf(buf[g].w, w2.w, acc[g][2]);                              \
    }                                                                           \
  }

  float4 bufA[8], bufB[8];
  LDB(bufA, 0, 0)
#pragma unroll 1
  for (int ch = 0; ch < 2; ++ch) {
    float acc[8][3];
#pragma unroll
    for (int g = 0; g < 8; ++g) {
      acc[g][0] = 0.f; acc[g][1] = 0.f; acc[g][2] = 0.f;
    }
#pragma unroll 1
    for (int jj = 0; jj < 6; ++jj) {
      const int j0 = 2 * jj, j1 = 2 * jj + 1;
      LDB(bufB, ch, j1)
      CPB(bufA, j0)
      if (jj < 5)      LDB(bufA, ch, j0 + 2)
      else if (ch < 1) LDB(bufA, 1, 0)     // cross-chunk prefetch
      CPB(bufB, j1)
    }
#pragma unroll
    for (int g = 0; g < 8; ++g) {
#pragma unroll
      for (int hh = 0; hh < 3; ++hh) {
        float s = acc[g][hh];
        s += __shfl_xor(s, 4);
        s += __shfl_xor(s, 2);
        s += __shfl_xor(s, 1);
        if (seg == 0)
          sm.attn[h0 + hh][ch * 64 + g * 8 + rowi] = s + sm.cb[h0 + hh];
      }
    }
  }
  __syncthreads();

  // coalesced store: log_ws[bl][h][nblk*128 .. +128), per-bl stride 768 f4
  for (int i = t; i < NHEAD * 128 / 4; i += 256) {
    const int h = i >> 5, nn4 = i & 31;
    ((float4*)log_ws)[(size_t)bl * (NHEAD * NN / 4) + h * (NN / 4) + nblk * 32 + nn4] =
        ((const float4*)sm.attn)[i];
  }
}

// =====================================================================
// C: softmax over n per (bl, h) + write out[b][n][l][h]. 768 blocks,
// XCD-chunked swizzle (adjacent-l partial-line writes merge in one L2).
// =====================================================================
__global__ __launch_bounds__(256)
void seqw_c(const float* __restrict__ log_ws, float* __restrict__ out)
{
  __shared__ float at[NHEAD][NN];
  __shared__ float smax[NHEAD], sinv[NHEAD];
  const int t    = threadIdx.x;
  const int lane = t & 63;
  const int wv   = t >> 6;
  const int i0   = blockIdx.x;
  const int bl   = (i0 & 7) * (NBL / 8) + (i0 >> 3);   // chunked XCD swizzle
  const int b    = bl / LL;
  const int l    = bl - b * LL;

  for (int i = t; i < NHEAD * NN / 4; i += 256)
    ((float4*)at)[i] = ((const float4*)log_ws)[(size_t)bl * (NHEAD * NN / 4) + i];
  __syncthreads();

#pragma unroll
  for (int jh = 0; jh < 3; ++jh) {
    const int h = wv * 3 + jh;
    float v0 = at[h][lane];
    float v1 = at[h][lane + 64];
    float v2 = at[h][lane + 128];
    float v3 = at[h][lane + 192];
    float mx = fmaxf(fmaxf(v0, v1), fmaxf(v2, v3));
#pragma unroll
    for (int m = 32; m; m >>= 1) mx = fmaxf(mx, __shfl_xor(mx, m));
    float s = __expf(v0 - mx) + __expf(v1 - mx) + __expf(v2 - mx) + __expf(v3 - mx);
#pragma unroll
    for (int m = 32; m; m >>= 1) s += __shfl_xor(s, m);
    if (lane == 0) { smax[h] = mx; sinv[h] = 1.0f / s; }
  }
  __syncthreads();

  {
    float o[NHEAD];
#pragma unroll
    for (int h = 0; h < NHEAD; ++h)
      o[h] = __expf(at[h][t] - smax[h]) * sinv[h];
    float* ob = out + ((size_t)(b * NN + t) * LL + l) * NHEAD;
    ((float4*)ob)[0] = make_float4(o[0], o[1], o[2],  o[3]);
    ((float4*)ob)[1] = make_float4(o[4], o[5], o[6],  o[7]);
    ((float4*)ob)[2] = make_float4(o[8], o[9], o[10], o[11]);
  }
}

// =====================================================================
// Fallback: fused single kernel (only if ws too small) — round-3 proven.
// =====================================================================
struct SmemF {
  float tar[D_MSA];
  float q[D_MSA];
  float wf[NHEAD][D_MSA];
  float cb[NHEAD];
  float smax[NHEAD];
  float sinv[NHEAD];
  float attn[NHEAD][NN];
};

__global__ __launch_bounds__(512, 2)
void seqw_fused_fb(const float* __restrict__ msa, const float* __restrict__ Wq,
                   const float* __restrict__ bq, const float* __restrict__ Wk,
                   const float* __restrict__ bk, float* __restrict__ out)
{
  __shared__ SmemF sm;
  const int t    = threadIdx.x;
  const int lane = t & 63;
  const int wv   = t >> 6;
  const int rowi = lane >> 4;
  const int seg  = lane & 15;
  const int bl   = blockIdx.x;
  const int b    = bl / LL;
  const int l    = bl - b * LL;
  const float scale = 0.17677669529663687f;

  const float* targ = msa + ((size_t)(b * NN) * LL + l) * D_MSA;
  if (t < 96) ((float4*)sm.tar)[t] = ((const float4*)targ)[t];
  __syncthreads();

  {
    float2 t2[3];
#pragma unroll
    for (int p = 0; p < 3; ++p) t2[p] = *(const float2*)&sm.tar[2 * lane + 128 * p];
#pragma unroll 1
    for (int j = 0; j < 48; ++j) {
      const int r = wv * 48 + j;
      const float* wr = Wq + (size_t)r * D_MSA;
      float s = 0.f;
#pragma unroll
      for (int p = 0; p < 3; ++p) {
        float2 w2 = *(const float2*)&wr[2 * lane + 128 * p];
        s = fmaf(t2[p].x, w2.x, s);
        s = fmaf(t2[p].y, w2.y, s);
      }
#pragma unroll
      for (int m = 32; m; m >>= 1) s += __shfl_xor(s, m);
      if (lane == 0) sm.q[r] = scale * (s + bq[r]);
    }
  }
  __syncthreads();

  if (t < D_MSA) {
    const int c = t;
    float a[NHEAD];
#pragma unroll
    for (int h = 0; h < NHEAD; ++h) a[h] = 0.f;
#pragma unroll 1
    for (int d = 0; d < DHID; ++d) {
#pragma unroll
      for (int h = 0; h < NHEAD; ++h)
        a[h] = fmaf(sm.q[h * DHID + d], Wk[(size_t)(h * DHID + d) * D_MSA + c], a[h]);
    }
#pragma unroll
    for (int h = 0; h < NHEAD; ++h) sm.wf[h][c] = a[h];
  }
  if (t < NHEAD) {
    float s = 0.f;
#pragma unroll
    for (int d = 0; d < DHID; ++d) s = fmaf(sm.q[t * DHID + d], bk[t * DHID + d], s);
    sm.cb[t] = s;
  }
  __syncthreads();

  const size_t rstride = (size_t)LL * D_MSA;
  const float* lanebase =
      msa + ((size_t)(b * NN + wv * 32 + rowi) * LL + l) * D_MSA + seg * 4;

#define LDF(buf, base, j)                                                       \
  {                                                                             \
    buf[0] = *(const float4*)((base) + 64 * (j));                               \
    buf[1] = *(const float4*)((base) + 4 * rstride + 64 * (j));                 \
  }
#define CPF(buf, j)                                                             \
  {                                                                             \
    _Pragma("unroll")                                                           \
    for (int h = 0; h < NHEAD; ++h) {                                           \
      float4 w4 = *(const float4*)&sm.wf[h][64 * (j) + 4 * seg];                \
      acc[0][h] = fmaf(buf[0].x, w4.x, acc[0][h]);                              \
      acc[0][h] = fmaf(buf[0].y, w4.y, acc[0][h]);                              \
      acc[0][h] = fmaf(buf[0].z, w4.z, acc[0][h]);                              \
      acc[0][h] = fmaf(buf[0].w, w4.w, acc[0][h]);                              \
      acc[1][h] = fmaf(buf[1].x, w4.x, acc[1][h]);                              \
      acc[1][h] = fmaf(buf[1].y, w4.y, acc[1][h]);                              \
      acc[1][h] = fmaf(buf[1].z, w4.z, acc[1][h]);                              \
      acc[1][h] = fmaf(buf[1].w, w4.w, acc[1][h]);                              \
    }                                                                           \
  }

  const float* pcur = lanebase;
  float4 bufA[2], bufB[2];
  LDF(bufA, pcur, 0)
#pragma unroll 1
  for (int ch = 0; ch < 4; ++ch) {
    float acc[2][NHEAD];
#pragma unroll
    for (int g = 0; g < 2; ++g)
#pragma unroll
      for (int h = 0; h < NHEAD; ++h) acc[g][h] = 0.f;
    const float* pnext = pcur + 8 * rstride;
    LDF(bufB, pcur, 1)  CPF(bufA, 0)
    LDF(bufA, pcur, 2)  CPF(bufB, 1)
    LDF(bufB, pcur, 3)  CPF(bufA, 2)
    LDF(bufA, pcur, 4)  CPF(bufB, 3)
    LDF(bufB, pcur, 5)  CPF(bufA, 4)
    if (ch < 3) LDF(bufA, pnext, 0)
    CPF(bufB, 5)
#pragma unroll
    for (int g = 0; g < 2; ++g) {
      const int n = wv * 32 + ch * 8 + g * 4 + rowi;
#pragma unroll
      for (int h = 0; h < NHEAD; ++h) {
        float s = acc[g][h];
        s += __shfl_xor(s, 8);
        s += __shfl_xor(s, 4);
        s += __shfl_xor(s, 2);
        s += __shfl_xor(s, 1);
        if (seg == 0) sm.attn[h][n] = s + sm.cb[h];
      }
    }
    pcur = pnext;
  }
  __syncthreads();

  if (wv < 6) {
#pragma unroll
    for (int jh = 0; jh < 2; ++jh) {
      const int h = wv * 2 + jh;
      float v0 = sm.attn[h][lane];
      float v1 = sm.attn[h][lane + 64];
      float v2 = sm.attn[h][lane + 128];
      float v3 = sm.attn[h][lane + 192];
      float mx = fmaxf(fmaxf(v0, v1), fmaxf(v2, v3));
#pragma unroll
      for (int m = 32; m; m >>= 1) mx = fmaxf(mx, __shfl_xor(mx, m));
      float s = __expf(v0 - mx) + __expf(v1 - mx) + __expf(v2 - mx) + __expf(v3 - mx);
#pragma unroll
      for (int m = 32; m; m >>= 1) s += __shfl_xor(s, m);
      if (lane == 0) { sm.smax[h] = mx; sm.sinv[h] = 1.0f / s; }
    }
  }
  __syncthreads();

  if (t < NN) {
    float o[NHEAD];
#pragma unroll
    for (int h = 0; h < NHEAD; ++h)
      o[h] = __expf(sm.attn[h][t] - sm.smax[h]) * sm.sinv[h];
    float* ob = out + ((size_t)(b * NN + t) * LL + l) * NHEAD;
    ((float4*)ob)[0] = make_float4(o[0], o[1], o[2],  o[3]);
    ((float4*)ob)[1] = make_float4(o[4], o[5], o[6],  o[7]);
    ((float4*)ob)[2] = make_float4(o[8], o[9], o[10], o[11]);
  }
}

extern "C" void kernel_launch(void* const* d_in, const int* in_sizes, int n_in,
                              void* d_out, int out_size, void* d_ws, size_t ws_size,
                              hipStream_t stream) {
  const float* msa = (const float*)d_in[0];
  const float* Wq  = (const float*)d_in[1];
  const float* bq  = (const float*)d_in[2];
  const float* Wk  = (const float*)d_in[3];
  const float* bk  = (const float*)d_in[4];
  float* out = (float*)d_out;

  if (ws_size >= WS_BYTES) {
    float* ws     = (float*)d_ws;
    float* wf_ws  = ws + WF_OFF;
    float* cb_ws  = ws + CB_OFF;
    float* log_ws = ws + LOG_OFF;
    seqw_a<<<dim3(NBL / 4), dim3(256), 0, stream>>>(msa, Wq, bq, Wk, bk, wf_ws, cb_ws);
    seqw_b<<<dim3(NBL * 2), dim3(256), 0, stream>>>(msa, wf_ws, cb_ws, log_ws);
    seqw_c<<<dim3(NBL), dim3(256), 0, stream>>>(log_ws, out);
  } else {
    seqw_fused_fb<<<dim3(NBL), dim3(512), 0, stream>>>(msa, Wq, bq, Wk, bk, out);
  }
}

// Round 11
// 160.444 us; speedup vs baseline: 1.1762x; 1.1762x over previous
//
#include <hip/hip_runtime.h>
#include <hip/hip_bf16.h>

#define D_MSA 384
#define NHEAD 12
#define DHID  32
#define BB    2
#define NN    256
#define LL    384
#define NBL   (BB * LL)          // 768 (b,l) pairs
#define WFROW (NHEAD * D_MSA)    // 4608

// ---- workspace layout (in floats) ----
#define WF_OFF 0
#define WF_SZ  ((size_t)NBL * WFROW)       // 3,538,944
#define Q_OFF  (WF_OFF + WF_SZ)
#define Q_SZ   ((size_t)NBL * D_MSA)       // 294,912
#define CB_OFF (Q_OFF + Q_SZ)
#define CB_SZ  ((size_t)NBL * NHEAD)       // 9,216
#define WS_FLOATS (CB_OFF + CB_SZ)
#define WS_BYTES  (WS_FLOATS * 4)

// =====================================================================
// A1: q[bl][c] = scale*(tar[bl] . Wq[c,:] + bq[c]); cb[bl][h] = q_h . bk_h
// 256 blocks x 3 bl-rows, 256 thr (round-9 proven).
// =====================================================================
__global__ __launch_bounds__(256)
void seqw_a1(const float* __restrict__ msa, const float* __restrict__ Wq,
             const float* __restrict__ bq, const float* __restrict__ bk,
             float* __restrict__ q_ws, float* __restrict__ cb_ws)
{
  __shared__ float tar[3][D_MSA];
  __shared__ float qs[3][D_MSA];
  const int t    = threadIdx.x;
  const int lane = t & 63;
  const int wv   = t >> 6;        // 0..3
  const int rowi = lane >> 4;     // 0..3
  const int seg  = lane & 15;     // 0..15
  const int bl0  = blockIdx.x * 3;
  const int b    = bl0 / LL, l0 = bl0 % LL;  // 3 | 384, never straddles b
  const float scale = 0.17677669529663687f;  // 1/sqrt(32)

  const float* base = msa + ((size_t)b * NN * LL + l0) * D_MSA;
  for (int i = t; i < 3 * D_MSA / 4; i += 256)
    ((float4*)tar)[i] = ((const float4*)base)[i];
  __syncthreads();

#pragma unroll 1
  for (int cc = 0; cc < 24; ++cc) {
    const int c = wv * 96 + cc * 4 + rowi;
    const float* wr = Wq + (size_t)c * D_MSA + seg * 4;
    float a0 = 0.f, a1 = 0.f, a2 = 0.f;
#pragma unroll
    for (int j = 0; j < 6; ++j) {
      float4 w4 = *(const float4*)(wr + 64 * j);
      float4 t0 = *(const float4*)&tar[0][64 * j + seg * 4];
      float4 t1 = *(const float4*)&tar[1][64 * j + seg * 4];
      float4 t2 = *(const float4*)&tar[2][64 * j + seg * 4];
      a0 = fmaf(w4.x, t0.x, a0); a0 = fmaf(w4.y, t0.y, a0);
      a0 = fmaf(w4.z, t0.z, a0); a0 = fmaf(w4.w, t0.w, a0);
      a1 = fmaf(w4.x, t1.x, a1); a1 = fmaf(w4.y, t1.y, a1);
      a1 = fmaf(w4.z, t1.z, a1); a1 = fmaf(w4.w, t1.w, a1);
      a2 = fmaf(w4.x, t2.x, a2); a2 = fmaf(w4.y, t2.y, a2);
      a2 = fmaf(w4.z, t2.z, a2); a2 = fmaf(w4.w, t2.w, a2);
    }
#pragma unroll
    for (int m = 8; m; m >>= 1) {
      a0 += __shfl_xor(a0, m);
      a1 += __shfl_xor(a1, m);
      a2 += __shfl_xor(a2, m);
    }
    if (seg == 0) {
      const float bqc = bq[c];
      const float q0 = scale * (a0 + bqc);
      const float q1 = scale * (a1 + bqc);
      const float q2 = scale * (a2 + bqc);
      qs[0][c] = q0; q_ws[(size_t)(bl0 + 0) * D_MSA + c] = q0;
      qs[1][c] = q1; q_ws[(size_t)(bl0 + 1) * D_MSA + c] = q1;
      qs[2][c] = q2; q_ws[(size_t)(bl0 + 2) * D_MSA + c] = q2;
    }
  }
  __syncthreads();

  if (t < 3 * NHEAD) {
    const int r = t / NHEAD, h = t % NHEAD;
    float s = 0.f;
#pragma unroll
    for (int d = 0; d < DHID; ++d)
      s = fmaf(qs[r][h * DHID + d], bk[h * DHID + d], s);
    cb_ws[(size_t)(bl0 + r) * NHEAD + h] = s;
  }
}

// =====================================================================
// A2: wf[bl][h][c] = sum_d q[bl][h*32+d] * Wk[h*32+d][c]
// grid 12h x 48 tiles of 16 bl-rows, 256 threads (round-9 proven).
// =====================================================================
__global__ __launch_bounds__(256)
void seqw_a2(const float* __restrict__ Wk, const float* __restrict__ q_ws,
             float* __restrict__ wf_ws)
{
  __shared__ float qt[16][DHID];
  const int t   = threadIdx.x;
  const int h   = blockIdx.x % NHEAD;
  const int bl0 = (blockIdx.x / NHEAD) * 16;

  if (t < 128) {
    const int r = t >> 3, j = (t & 7) * 4;
    *(float4*)&qt[r][j] =
        *(const float4*)(q_ws + (size_t)(bl0 + r) * D_MSA + h * DHID + j);
  }
  __syncthreads();

#pragma unroll 1
  for (int pass = 0; pass < 2; ++pass) {
    const int c = pass * 256 + t;
    if (c < D_MSA) {
      float acc[16];
#pragma unroll
      for (int r = 0; r < 16; ++r) acc[r] = 0.f;
      const float* wkb = Wk + (size_t)(h * DHID) * D_MSA + c;
#pragma unroll 2
      for (int d = 0; d < DHID; d += 4) {
        const float w0 = wkb[(size_t)(d + 0) * D_MSA];
        const float w1 = wkb[(size_t)(d + 1) * D_MSA];
        const float w2 = wkb[(size_t)(d + 2) * D_MSA];
        const float w3 = wkb[(size_t)(d + 3) * D_MSA];
#pragma unroll
        for (int r = 0; r < 16; ++r) {
          float4 q4 = *(const float4*)&qt[r][d];
          acc[r] = fmaf(q4.x, w0, acc[r]);
          acc[r] = fmaf(q4.y, w1, acc[r]);
          acc[r] = fmaf(q4.z, w2, acc[r]);
          acc[r] = fmaf(q4.w, w3, acc[r]);
        }
      }
#pragma unroll
      for (int r = 0; r < 16; ++r)
        wf_ws[(size_t)(bl0 + r) * WFROW + h * D_MSA + c] = acc[r];
    }
  }
}

// =====================================================================
// B: one block per (b,l), 256 thr = 4 waves. Full fused tail: logits +
// softmax + output write (no log_ws, no C kernel).
// Wave wv owns heads {3wv..3wv+2} and ALL 256 rows (4 chunks of 64);
// msa re-read x4 across waves is L1-served (waves run the same address
// sequence). Lanes = 8 rowi x 8 seg; per LD instr 8-lane seg groups read
// 128B contiguous. G=8 rows amortize each w4 read (8 distinct 16B slots
// = 32 banks, 8x broadcast: conflict-free). acc[8][3]=24 regs. 3-stage
// shfl reduce. NO min-occupancy launch_bounds (spill trap, r2/5/6).
// LDS ~31 KB -> 5 blocks/CU cap; 768 blocks = 3/CU, one residency round.
// =====================================================================
struct SmemB {
  float wf[NHEAD][D_MSA];   // 18 KB
  float cb[NHEAD];
  float attn[NHEAD][NN];    // 12 KB
  float smax[NHEAD];
  float sinv[NHEAD];
};

__global__ __launch_bounds__(256)
void seqw_b(const float* __restrict__ msa, const float* __restrict__ wf_ws,
            const float* __restrict__ cb_ws, float* __restrict__ out)
{
  __shared__ SmemB sm;
  const int t    = threadIdx.x;
  const int lane = t & 63;
  const int wv   = t >> 6;        // 0..3
  const int rowi = lane >> 3;     // 0..7
  const int seg  = lane & 7;      // 0..7 : 8 lanes cover 32 c per j-step
  const int bl   = blockIdx.x;
  const int b    = bl / LL;
  const int l    = bl - b * LL;
  const int h0   = 3 * wv;

  // stage wf slice (1152 float4, coalesced, disjoint per block) + cb
  {
    const float4* src = (const float4*)(wf_ws + (size_t)bl * WFROW);
    for (int i = t; i < WFROW / 4; i += 256) ((float4*)sm.wf)[i] = src[i];
    if (t < NHEAD) sm.cb[t] = cb_ws[(size_t)bl * NHEAD + t];
  }
  __syncthreads();

  const size_t rstride = (size_t)LL * D_MSA;
  const float* lanebase =
      msa + ((size_t)(b * NN + rowi) * LL + l) * D_MSA + seg * 4;

  // LDB: 8 row-groups; 8-lane seg group reads 128B contiguous per row
#define LDB(buf, ch, j)                                                         \
  {                                                                             \
    _Pragma("unroll")                                                           \
    for (int g = 0; g < 8; ++g)                                                 \
      buf[g] = *(const float4*)(lanebase +                                      \
                 (size_t)((ch) * 64 + g * 8) * rstride + 32 * (j));             \
  }
  // CPB: 3 w4 reads serve 8 rows x 3 heads
#define CPB(buf, j)                                                             \
  {                                                                             \
    float4 w0 = *(const float4*)&sm.wf[h0 + 0][32 * (j) + 4 * seg];             \
    float4 w1 = *(const float4*)&sm.wf[h0 + 1][32 * (j) + 4 * seg];             \
    float4 w2 = *(const float4*)&sm.wf[h0 + 2][32 * (j) + 4 * seg];             \
    _Pragma("unroll")                                                           \
    for (int g = 0; g < 8; ++g) {                                               \
      acc[g][0] = fmaf(buf[g].x, w0.x, acc[g][0]);                              \
      acc[g][0] = fmaf(buf[g].y, w0.y, acc[g][0]);                              \
      acc[g][0] = fmaf(buf[g].z, w0.z, acc[g][0]);                              \
      acc[g][0] = fmaf(buf[g].w, w0.w, acc[g][0]);                              \
      acc[g][1] = fmaf(buf[g].x, w1.x, acc[g][1]);                              \
      acc[g][1] = fmaf(buf[g].y, w1.y, acc[g][1]);                              \
      acc[g][1] = fmaf(buf[g].z, w1.z, acc[g][1]);                              \
      acc[g][1] = fmaf(buf[g].w, w1.w, acc[g][1]);                              \
      acc[g][2] = fmaf(buf[g].x, w2.x, acc[g][2]);                              \
      acc[g][2] = fmaf(buf[g].y, w2.y, acc[g][2]);                              \
      acc[g][2] = fmaf(buf[g].z, w2.z, acc[g][2]);                              \
      acc[g][2] = fmaf(buf[g].w, w2.w, acc[g][2]);                              \
    }                                                                           \
  }

  float4 bufA[8], bufB[8];
  LDB(bufA, 0, 0)
#pragma unroll 1
  for (int ch = 0; ch < 4; ++ch) {
    float acc[8][3];
#pragma unroll
    for (int g = 0; g < 8; ++g) {
      acc[g][0] = 0.f; acc[g][1] = 0.f; acc[g][2] = 0.f;
    }
#pragma unroll 1
    for (int jj = 0; jj < 6; ++jj) {
      const int j0 = 2 * jj, j1 = 2 * jj + 1;
      LDB(bufB, ch, j1)
      CPB(bufA, j0)
      if (jj < 5)      LDB(bufA, ch, j0 + 2)
      else if (ch < 3) LDB(bufA, ch + 1, 0)   // cross-chunk prefetch
      CPB(bufB, j1)
    }
    // reduce over the 8-seg group (3 stages), write logits + cb
#pragma unroll
    for (int g = 0; g < 8; ++g) {
#pragma unroll
      for (int hh = 0; hh < 3; ++hh) {
        float s = acc[g][hh];
        s += __shfl_xor(s, 4);
        s += __shfl_xor(s, 2);
        s += __shfl_xor(s, 1);
        if (seg == 0)
          sm.attn[h0 + hh][ch * 64 + g * 8 + rowi] = s + sm.cb[h0 + hh];
      }
    }
  }
  __syncthreads();

  // softmax over n: 4 waves x 3 heads each (round-7 proven tail)
#pragma unroll
  for (int jh = 0; jh < 3; ++jh) {
    const int h = wv * 3 + jh;
    float v0 = sm.attn[h][lane];
    float v1 = sm.attn[h][lane + 64];
    float v2 = sm.attn[h][lane + 128];
    float v3 = sm.attn[h][lane + 192];
    float mx = fmaxf(fmaxf(v0, v1), fmaxf(v2, v3));
#pragma unroll
    for (int m = 32; m; m >>= 1) mx = fmaxf(mx, __shfl_xor(mx, m));
    float s = __expf(v0 - mx) + __expf(v1 - mx) + __expf(v2 - mx) + __expf(v3 - mx);
#pragma unroll
    for (int m = 32; m; m >>= 1) s += __shfl_xor(s, m);
    if (lane == 0) { sm.smax[h] = mx; sm.sinv[h] = 1.0f / s; }
  }
  __syncthreads();

  // write out[b, n=t, l, :] (3 float4 stores per thread)
  {
    float o[NHEAD];
#pragma unroll
    for (int h = 0; h < NHEAD; ++h)
      o[h] = __expf(sm.attn[h][t] - sm.smax[h]) * sm.sinv[h];
    float* ob = out + ((size_t)(b * NN + t) * LL + l) * NHEAD;
    ((float4*)ob)[0] = make_float4(o[0], o[1], o[2],  o[3]);
    ((float4*)ob)[1] = make_float4(o[4], o[5], o[6],  o[7]);
    ((float4*)ob)[2] = make_float4(o[8], o[9], o[10], o[11]);
  }
}

// =====================================================================
// Fallback: fused single kernel (only if ws too small) — round-3 proven.
// =====================================================================
struct SmemF {
  float tar[D_MSA];
  float q[D_MSA];
  float wf[NHEAD][D_MSA];
  float cb[NHEAD];
  float smax[NHEAD];
  float sinv[NHEAD];
  float attn[NHEAD][NN];
};

__global__ __launch_bounds__(512, 2)
void seqw_fused_fb(const float* __restrict__ msa, const float* __restrict__ Wq,
                   const float* __restrict__ bq, const float* __restrict__ Wk,
                   const float* __restrict__ bk, float* __restrict__ out)
{
  __shared__ SmemF sm;
  const int t    = threadIdx.x;
  const int lane = t & 63;
  const int wv   = t >> 6;
  const int rowi = lane >> 4;
  const int seg  = lane & 15;
  const int bl   = blockIdx.x;
  const int b    = bl / LL;
  const int l    = bl - b * LL;
  const float scale = 0.17677669529663687f;

  const float* targ = msa + ((size_t)(b * NN) * LL + l) * D_MSA;
  if (t < 96) ((float4*)sm.tar)[t] = ((const float4*)targ)[t];
  __syncthreads();

  {
    float2 t2[3];
#pragma unroll
    for (int p = 0; p < 3; ++p) t2[p] = *(const float2*)&sm.tar[2 * lane + 128 * p];
#pragma unroll 1
    for (int j = 0; j < 48; ++j) {
      const int r = wv * 48 + j;
      const float* wr = Wq + (size_t)r * D_MSA;
      float s = 0.f;
#pragma unroll
      for (int p = 0; p < 3; ++p) {
        float2 w2 = *(const float2*)&wr[2 * lane + 128 * p];
        s = fmaf(t2[p].x, w2.x, s);
        s = fmaf(t2[p].y, w2.y, s);
      }
#pragma unroll
      for (int m = 32; m; m >>= 1) s += __shfl_xor(s, m);
      if (lane == 0) sm.q[r] = scale * (s + bq[r]);
    }
  }
  __syncthreads();

  if (t < D_MSA) {
    const int c = t;
    float a[NHEAD];
#pragma unroll
    for (int h = 0; h < NHEAD; ++h) a[h] = 0.f;
#pragma unroll 1
    for (int d = 0; d < DHID; ++d) {
#pragma unroll
      for (int h = 0; h < NHEAD; ++h)
        a[h] = fmaf(sm.q[h * DHID + d], Wk[(size_t)(h * DHID + d) * D_MSA + c], a[h]);
    }
#pragma unroll
    for (int h = 0; h < NHEAD; ++h) sm.wf[h][c] = a[h];
  }
  if (t < NHEAD) {
    float s = 0.f;
#pragma unroll
    for (int d = 0; d < DHID; ++d) s = fmaf(sm.q[t * DHID + d], bk[t * DHID + d], s);
    sm.cb[t] = s;
  }
  __syncthreads();

  const size_t rstride = (size_t)LL * D_MSA;
  const float* lanebase =
      msa + ((size_t)(b * NN + wv * 32 + rowi) * LL + l) * D_MSA + seg * 4;

#define LDF(buf, base, j)                                                       \
  {                                                                             \
    buf[0] = *(const float4*)((base) + 64 * (j));                               \
    buf[1] = *(const float4*)((base) + 4 * rstride + 64 * (j));                 \
  }
#define CPF(buf, j)                                                             \
  {                                                                             \
    _Pragma("unroll")                                                           \
    for (int h = 0; h < NHEAD; ++h) {                                           \
      float4 w4 = *(const float4*)&sm.wf[h][64 * (j) + 4 * seg];                \
      acc[0][h] = fmaf(buf[0].x, w4.x, acc[0][h]);                              \
      acc[0][h] = fmaf(buf[0].y, w4.y, acc[0][h]);                              \
      acc[0][h] = fmaf(buf[0].z, w4.z, acc[0][h]);                              \
      acc[0][h] = fmaf(buf[0].w, w4.w, acc[0][h]);                              \
      acc[1][h] = fmaf(buf[1].x, w4.x, acc[1][h]);                              \
      acc[1][h] = fmaf(buf[1].y, w4.y, acc[1][h]);                              \
      acc[1][h] = fmaf(buf[1].z, w4.z, acc[1][h]);                              \
      acc[1][h] = fmaf(buf[1].w, w4.w, acc[1][h]);                              \
    }                                                                           \
  }

  const float* pcur = lanebase;
  float4 bufA[2], bufB[2];
  LDF(bufA, pcur, 0)
#pragma unroll 1
  for (int ch = 0; ch < 4; ++ch) {
    float acc[2][NHEAD];
#pragma unroll
    for (int g = 0; g < 2; ++g)
#pragma unroll
      for (int h = 0; h < NHEAD; ++h) acc[g][h] = 0.f;
    const float* pnext = pcur + 8 * rstride;
    LDF(bufB, pcur, 1)  CPF(bufA, 0)
    LDF(bufA, pcur, 2)  CPF(bufB, 1)
    LDF(bufB, pcur, 3)  CPF(bufA, 2)
    LDF(bufA, pcur, 4)  CPF(bufB, 3)
    LDF(bufB, pcur, 5)  CPF(bufA, 4)
    if (ch < 3) LDF(bufA, pnext, 0)
    CPF(bufB, 5)
#pragma unroll
    for (int g = 0; g < 2; ++g) {
      const int n = wv * 32 + ch * 8 + g * 4 + rowi;
#pragma unroll
      for (int h = 0; h < NHEAD; ++h) {
        float s = acc[g][h];
        s += __shfl_xor(s, 8);
        s += __shfl_xor(s, 4);
        s += __shfl_xor(s, 2);
        s += __shfl_xor(s, 1);
        if (seg == 0) sm.attn[h][n] = s + sm.cb[h];
      }
    }
    pcur = pnext;
  }
  __syncthreads();

  if (wv < 6) {
#pragma unroll
    for (int jh = 0; jh < 2; ++jh) {
      const int h = wv * 2 + jh;
      float v0 = sm.attn[h][lane];
      float v1 = sm.attn[h][lane + 64];
      float v2 = sm.attn[h][lane + 128];
      float v3 = sm.attn[h][lane + 192];
      float mx = fmaxf(fmaxf(v0, v1), fmaxf(v2, v3));
#pragma unroll
      for (int m = 32; m; m >>= 1) mx = fmaxf(mx, __shfl_xor(mx, m));
      float s = __expf(v0 - mx) + __expf(v1 - mx) + __expf(v2 - mx) + __expf(v3 - mx);
#pragma unroll
      for (int m = 32; m; m >>= 1) s += __shfl_xor(s, m);
      if (lane == 0) { sm.smax[h] = mx; sm.sinv[h] = 1.0f / s; }
    }
  }
  __syncthreads();

  if (t < NN) {
    float o[NHEAD];
#pragma unroll
    for (int h = 0; h < NHEAD; ++h)
      o[h] = __expf(sm.attn[h][t] - sm.smax[h]) * sm.sinv[h];
    float* ob = out + ((size_t)(b * NN + t) * LL + l) * NHEAD;
    ((float4*)ob)[0] = make_float4(o[0], o[1], o[2],  o[3]);
    ((float4*)ob)[1] = make_float4(o[4], o[5], o[6],  o[7]);
    ((float4*)ob)[2] = make_float4(o[8], o[9], o[10], o[11]);
  }
}

extern "C" void kernel_launch(void* const* d_in, const int* in_sizes, int n_in,
                              void* d_out, int out_size, void* d_ws, size_t ws_size,
                              hipStream_t stream) {
  const float* msa = (const float*)d_in[0];
  const float* Wq  = (const float*)d_in[1];
  const float* bq  = (const float*)d_in[2];
  const float* Wk  = (const float*)d_in[3];
  const float* bk  = (const float*)d_in[4];
  float* out = (float*)d_out;

  if (ws_size >= WS_BYTES) {
    float* ws    = (float*)d_ws;
    float* wf_ws = ws + WF_OFF;
    float* q_ws  = ws + Q_OFF;
    float* cb_ws = ws + CB_OFF;
    seqw_a1<<<dim3(NBL / 3), dim3(256), 0, stream>>>(msa, Wq, bq, bk, q_ws, cb_ws);
    seqw_a2<<<dim3(NHEAD * (NBL / 16)), dim3(256), 0, stream>>>(Wk, q_ws, wf_ws);
    seqw_b<<<dim3(NBL), dim3(256), 0, stream>>>(msa, wf_ws, cb_ws, out);
  } else {
    seqw_fused_fb<<<dim3(NBL), dim3(512), 0, stream>>>(msa, Wq, bq, Wk, bk, out);
  }
}

// Round 12
// 129.680 us; speedup vs baseline: 1.4552x; 1.2372x over previous
//
#include <hip/hip_runtime.h>
#include <hip/hip_bf16.h>

#define D_MSA 384
#define NHEAD 12
#define DHID  32
#define BB    2
#define NN    256
#define LL    384
#define NBL   (BB * LL)          // 768 (b,l) pairs
#define WFROW (NHEAD * D_MSA)    // 4608

// ---- workspace layout (in floats) ----
#define WF_OFF 0
#define WF_SZ  ((size_t)NBL * WFROW)       // 3,538,944
#define Q_OFF  (WF_OFF + WF_SZ)
#define Q_SZ   ((size_t)NBL * D_MSA)       // 294,912
#define CB_OFF (Q_OFF + Q_SZ)
#define CB_SZ  ((size_t)NBL * NHEAD)       // 9,216
#define LOG_OFF (CB_OFF + CB_SZ)
#define LOG_SZ ((size_t)NBL * NHEAD * NN)  // 2,359,296
#define WS_FLOATS (LOG_OFF + LOG_SZ)
#define WS_BYTES  (WS_FLOATS * 4)

// =====================================================================
// A1: q[bl][c] = scale*(tar[bl] . Wq[c,:] + bq[c]); cb[bl][h] = q_h . bk_h
// 256 blocks x 3 bl-rows, 256 thr (round-9 proven, unchanged).
// =====================================================================
__global__ __launch_bounds__(256)
void seqw_a1(const float* __restrict__ msa, const float* __restrict__ Wq,
             const float* __restrict__ bq, const float* __restrict__ bk,
             float* __restrict__ q_ws, float* __restrict__ cb_ws)
{
  __shared__ float tar[3][D_MSA];
  __shared__ float qs[3][D_MSA];
  const int t    = threadIdx.x;
  const int lane = t & 63;
  const int wv   = t >> 6;        // 0..3
  const int rowi = lane >> 4;     // 0..3
  const int seg  = lane & 15;     // 0..15
  const int bl0  = blockIdx.x * 3;
  const int b    = bl0 / LL, l0 = bl0 % LL;  // 3 | 384, never straddles b
  const float scale = 0.17677669529663687f;  // 1/sqrt(32)

  const float* base = msa + ((size_t)b * NN * LL + l0) * D_MSA;
  for (int i = t; i < 3 * D_MSA / 4; i += 256)
    ((float4*)tar)[i] = ((const float4*)base)[i];
  __syncthreads();

#pragma unroll 1
  for (int cc = 0; cc < 24; ++cc) {
    const int c = wv * 96 + cc * 4 + rowi;
    const float* wr = Wq + (size_t)c * D_MSA + seg * 4;
    float a0 = 0.f, a1 = 0.f, a2 = 0.f;
#pragma unroll
    for (int j = 0; j < 6; ++j) {
      float4 w4 = *(const float4*)(wr + 64 * j);
      float4 t0 = *(const float4*)&tar[0][64 * j + seg * 4];
      float4 t1 = *(const float4*)&tar[1][64 * j + seg * 4];
      float4 t2 = *(const float4*)&tar[2][64 * j + seg * 4];
      a0 = fmaf(w4.x, t0.x, a0); a0 = fmaf(w4.y, t0.y, a0);
      a0 = fmaf(w4.z, t0.z, a0); a0 = fmaf(w4.w, t0.w, a0);
      a1 = fmaf(w4.x, t1.x, a1); a1 = fmaf(w4.y, t1.y, a1);
      a1 = fmaf(w4.z, t1.z, a1); a1 = fmaf(w4.w, t1.w, a1);
      a2 = fmaf(w4.x, t2.x, a2); a2 = fmaf(w4.y, t2.y, a2);
      a2 = fmaf(w4.z, t2.z, a2); a2 = fmaf(w4.w, t2.w, a2);
    }
#pragma unroll
    for (int m = 8; m; m >>= 1) {
      a0 += __shfl_xor(a0, m);
      a1 += __shfl_xor(a1, m);
      a2 += __shfl_xor(a2, m);
    }
    if (seg == 0) {
      const float bqc = bq[c];
      const float q0 = scale * (a0 + bqc);
      const float q1 = scale * (a1 + bqc);
      const float q2 = scale * (a2 + bqc);
      qs[0][c] = q0; q_ws[(size_t)(bl0 + 0) * D_MSA + c] = q0;
      qs[1][c] = q1; q_ws[(size_t)(bl0 + 1) * D_MSA + c] = q1;
      qs[2][c] = q2; q_ws[(size_t)(bl0 + 2) * D_MSA + c] = q2;
    }
  }
  __syncthreads();

  if (t < 3 * NHEAD) {
    const int r = t / NHEAD, h = t % NHEAD;
    float s = 0.f;
#pragma unroll
    for (int d = 0; d < DHID; ++d)
      s = fmaf(qs[r][h * DHID + d], bk[h * DHID + d], s);
    cb_ws[(size_t)(bl0 + r) * NHEAD + h] = s;
  }
}

// =====================================================================
// A2: wf[bl][h][c] = sum_d q[bl][h*32+d] * Wk[h*32+d][c]
// grid 12h x 48 tiles of 16 bl-rows, 256 threads (round-9 proven).
// =====================================================================
__global__ __launch_bounds__(256)
void seqw_a2(const float* __restrict__ Wk, const float* __restrict__ q_ws,
             float* __restrict__ wf_ws)
{
  __shared__ float qt[16][DHID];
  const int t   = threadIdx.x;
  const int h   = blockIdx.x % NHEAD;
  const int bl0 = (blockIdx.x / NHEAD) * 16;

  if (t < 128) {
    const int r = t >> 3, j = (t & 7) * 4;
    *(float4*)&qt[r][j] =
        *(const float4*)(q_ws + (size_t)(bl0 + r) * D_MSA + h * DHID + j);
  }
  __syncthreads();

#pragma unroll 1
  for (int pass = 0; pass < 2; ++pass) {
    const int c = pass * 256 + t;
    if (c < D_MSA) {
      float acc[16];
#pragma unroll
      for (int r = 0; r < 16; ++r) acc[r] = 0.f;
      const float* wkb = Wk + (size_t)(h * DHID) * D_MSA + c;
#pragma unroll 2
      for (int d = 0; d < DHID; d += 4) {
        const float w0 = wkb[(size_t)(d + 0) * D_MSA];
        const float w1 = wkb[(size_t)(d + 1) * D_MSA];
        const float w2 = wkb[(size_t)(d + 2) * D_MSA];
        const float w3 = wkb[(size_t)(d + 3) * D_MSA];
#pragma unroll
        for (int r = 0; r < 16; ++r) {
          float4 q4 = *(const float4*)&qt[r][d];
          acc[r] = fmaf(q4.x, w0, acc[r]);
          acc[r] = fmaf(q4.y, w1, acc[r]);
          acc[r] = fmaf(q4.z, w2, acc[r]);
          acc[r] = fmaf(q4.w, w3, acc[r]);
        }
      }
#pragma unroll
      for (int r = 0; r < 16; ++r)
        wf_ws[(size_t)(bl0 + r) * WFROW + h * D_MSA + c] = acc[r];
    }
  }
}

// =====================================================================
// B: logits only. Grid 3072 = (bl, n-quarter); 256 thr = 4 waves.
// Wave wv: head-group hg = wv&1 (6 heads), row-half rq = wv>>1 (32 of
// the 64 rows). msa re-read x2 (was x4); single chunk per wave.
// Lanes = 8 rowi x 8 seg: per LD instr 8-lane groups read 128B
// contiguous per row. G=4 rows amortize each w4 read (8 distinct 16B
// slots = 32 banks, 8x broadcast: conflict-free). acc[4][6]=24 regs +
// 2x4 float4 bufs (~85 VGPR). 3-stage shfl reduce over the seg group.
// NO min-occupancy launch_bounds (spill trap, r2/5/6).
// =====================================================================
__global__ __launch_bounds__(256)
void seqw_b(const float* __restrict__ msa, const float* __restrict__ wf_ws,
            const float* __restrict__ cb_ws, float* __restrict__ log_ws)
{
  __shared__ float wf_s[NHEAD][D_MSA];   // 18 KB
  __shared__ float cb_s[NHEAD];
  __shared__ float attn_s[NHEAD][64];    // 3 KB
  const int t    = threadIdx.x;
  const int lane = t & 63;
  const int wv   = t >> 6;        // 0..3
  const int hg   = wv & 1;        // head group: h0 = 6*hg
  const int rq   = wv >> 1;       // row half: rows [rq*32, rq*32+32)
  const int h0   = 6 * hg;
  const int rowi = lane >> 3;     // 0..7
  const int seg  = lane & 7;      // 0..7 : 8 lanes cover 32 c per j-step
  const int bid  = blockIdx.x;
  const int bl   = bid >> 2;
  const int nq   = bid & 3;       // which 64-row quarter
  const int b    = bl / LL;
  const int l    = bl - b * LL;

  // stage wf slice (1152 float4, coalesced; shared by 4 n-quarters via L2)
  {
    const float4* src = (const float4*)(wf_ws + (size_t)bl * WFROW);
    for (int i = t; i < WFROW / 4; i += 256) ((float4*)wf_s)[i] = src[i];
    if (t < NHEAD) cb_s[t] = cb_ws[(size_t)bl * NHEAD + t];
  }
  __syncthreads();

  const size_t rstride = (size_t)LL * D_MSA;
  const float* lanebase =
      msa + ((size_t)(b * NN + nq * 64 + rq * 32 + rowi) * LL + l) * D_MSA + seg * 4;

  // LDB: 4 row-groups; 8-lane seg group reads 128B contiguous per row
#define LDB(buf, j)                                                             \
  {                                                                             \
    _Pragma("unroll")                                                           \
    for (int g = 0; g < 4; ++g)                                                 \
      buf[g] = *(const float4*)(lanebase + (size_t)(g * 8) * rstride + 32 * (j)); \
  }
  // CPB: 6 w4 reads serve 4 rows x 6 heads
#define CPB(buf, j)                                                             \
  {                                                                             \
    _Pragma("unroll")                                                           \
    for (int hh = 0; hh < 6; ++hh) {                                            \
      float4 w4 = *(const float4*)&wf_s[h0 + hh][32 * (j) + 4 * seg];           \
      _Pragma("unroll")                                                         \
      for (int g = 0; g < 4; ++g) {                                             \
        acc[g][hh] = fmaf(buf[g].x, w4.x, acc[g][hh]);                          \
        acc[g][hh] = fmaf(buf[g].y, w4.y, acc[g][hh]);                          \
        acc[g][hh] = fmaf(buf[g].z, w4.z, acc[g][hh]);                          \
        acc[g][hh] = fmaf(buf[g].w, w4.w, acc[g][hh]);                          \
      }                                                                         \
    }                                                                           \
  }

  float acc[4][6];
#pragma unroll
  for (int g = 0; g < 4; ++g)
#pragma unroll
    for (int hh = 0; hh < 6; ++hh) acc[g][hh] = 0.f;

  float4 bufA[4], bufB[4];
  LDB(bufA, 0)
#pragma unroll 1
  for (int jj = 0; jj < 6; ++jj) {
    const int j0 = 2 * jj, j1 = 2 * jj + 1;
    LDB(bufB, j1)
    CPB(bufA, j0)
    if (jj < 5) LDB(bufA, j0 + 2)
    CPB(bufB, j1)
  }

  // reduce over the 8-seg group (3 stages), write logits + cb to LDS
#pragma unroll
  for (int g = 0; g < 4; ++g) {
#pragma unroll
    for (int hh = 0; hh < 6; ++hh) {
      float s = acc[g][hh];
      s += __shfl_xor(s, 4);
      s += __shfl_xor(s, 2);
      s += __shfl_xor(s, 1);
      if (seg == 0)
        attn_s[h0 + hh][rq * 32 + g * 8 + rowi] = s + cb_s[h0 + hh];
    }
  }
  __syncthreads();

  // coalesced store: log_ws[bl][h][nq*64 .. +64), per-bl stride 768 f4
  for (int i = t; i < NHEAD * 64 / 4; i += 256) {
    const int h = i >> 4, r4 = i & 15;
    ((float4*)log_ws)[(size_t)bl * (NHEAD * NN / 4) + h * (NN / 4) + nq * 16 + r4] =
        ((const float4*)attn_s)[i];
  }
}

// =====================================================================
// C: softmax over n per (bl, h) + write out[b][n][l][h]. 768 blocks
// (round-9 proven, unchanged).
// =====================================================================
__global__ __launch_bounds__(256)
void seqw_c(const float* __restrict__ log_ws, float* __restrict__ out)
{
  __shared__ float at[NHEAD][NN];
  __shared__ float smax[NHEAD], sinv[NHEAD];
  const int t    = threadIdx.x;
  const int lane = t & 63;
  const int wv   = t >> 6;
  const int bl   = blockIdx.x;
  const int b    = bl / LL;
  const int l    = bl - b * LL;

  for (int i = t; i < NHEAD * NN / 4; i += 256)
    ((float4*)at)[i] = ((const float4*)log_ws)[(size_t)bl * (NHEAD * NN / 4) + i];
  __syncthreads();

#pragma unroll
  for (int jh = 0; jh < 3; ++jh) {
    const int h = wv * 3 + jh;
    float v0 = at[h][lane];
    float v1 = at[h][lane + 64];
    float v2 = at[h][lane + 128];
    float v3 = at[h][lane + 192];
    float mx = fmaxf(fmaxf(v0, v1), fmaxf(v2, v3));
#pragma unroll
    for (int m = 32; m; m >>= 1) mx = fmaxf(mx, __shfl_xor(mx, m));
    float s = __expf(v0 - mx) + __expf(v1 - mx) + __expf(v2 - mx) + __expf(v3 - mx);
#pragma unroll
    for (int m = 32; m; m >>= 1) s += __shfl_xor(s, m);
    if (lane == 0) { smax[h] = mx; sinv[h] = 1.0f / s; }
  }
  __syncthreads();

  {
    float o[NHEAD];
#pragma unroll
    for (int h = 0; h < NHEAD; ++h)
      o[h] = __expf(at[h][t] - smax[h]) * sinv[h];
    float* ob = out + ((size_t)(b * NN + t) * LL + l) * NHEAD;
    ((float4*)ob)[0] = make_float4(o[0], o[1], o[2],  o[3]);
    ((float4*)ob)[1] = make_float4(o[4], o[5], o[6],  o[7]);
    ((float4*)ob)[2] = make_float4(o[8], o[9], o[10], o[11]);
  }
}

// =====================================================================
// Fallback: fused single kernel (only if ws too small) — round-3 proven.
// =====================================================================
struct SmemF {
  float tar[D_MSA];
  float q[D_MSA];
  float wf[NHEAD][D_MSA];
  float cb[NHEAD];
  float smax[NHEAD];
  float sinv[NHEAD];
  float attn[NHEAD][NN];
};

__global__ __launch_bounds__(512, 2)
void seqw_fused_fb(const float* __restrict__ msa, const float* __restrict__ Wq,
                   const float* __restrict__ bq, const float* __restrict__ Wk,
                   const float* __restrict__ bk, float* __restrict__ out)
{
  __shared__ SmemF sm;
  const int t    = threadIdx.x;
  const int lane = t & 63;
  const int wv   = t >> 6;
  const int rowi = lane >> 4;
  const int seg  = lane & 15;
  const int bl   = blockIdx.x;
  const int b    = bl / LL;
  const int l    = bl - b * LL;
  const float scale = 0.17677669529663687f;

  const float* targ = msa + ((size_t)(b * NN) * LL + l) * D_MSA;
  if (t < 96) ((float4*)sm.tar)[t] = ((const float4*)targ)[t];
  __syncthreads();

  {
    float2 t2[3];
#pragma unroll
    for (int p = 0; p < 3; ++p) t2[p] = *(const float2*)&sm.tar[2 * lane + 128 * p];
#pragma unroll 1
    for (int j = 0; j < 48; ++j) {
      const int r = wv * 48 + j;
      const float* wr = Wq + (size_t)r * D_MSA;
      float s = 0.f;
#pragma unroll
      for (int p = 0; p < 3; ++p) {
        float2 w2 = *(const float2*)&wr[2 * lane + 128 * p];
        s = fmaf(t2[p].x, w2.x, s);
        s = fmaf(t2[p].y, w2.y, s);
      }
#pragma unroll
      for (int m = 32; m; m >>= 1) s += __shfl_xor(s, m);
      if (lane == 0) sm.q[r] = scale * (s + bq[r]);
    }
  }
  __syncthreads();

  if (t < D_MSA) {
    const int c = t;
    float a[NHEAD];
#pragma unroll
    for (int h = 0; h < NHEAD; ++h) a[h] = 0.f;
#pragma unroll 1
    for (int d = 0; d < DHID; ++d) {
#pragma unroll
      for (int h = 0; h < NHEAD; ++h)
        a[h] = fmaf(sm.q[h * DHID + d], Wk[(size_t)(h * DHID + d) * D_MSA + c], a[h]);
    }
#pragma unroll
    for (int h = 0; h < NHEAD; ++h) sm.wf[h][c] = a[h];
  }
  if (t < NHEAD) {
    float s = 0.f;
#pragma unroll
    for (int d = 0; d < DHID; ++d) s = fmaf(sm.q[t * DHID + d], bk[t * DHID + d], s);
    sm.cb[t] = s;
  }
  __syncthreads();

  const size_t rstride = (size_t)LL * D_MSA;
  const float* lanebase =
      msa + ((size_t)(b * NN + wv * 32 + rowi) * LL + l) * D_MSA + seg * 4;

#define LDF(buf, base, j)                                                       \
  {                                                                             \
    buf[0] = *(const float4*)((base) + 64 * (j));                               \
    buf[1] = *(const float4*)((base) + 4 * rstride + 64 * (j));                 \
  }
#define CPF(buf, j)                                                             \
  {                                                                             \
    _Pragma("unroll")                                                           \
    for (int h = 0; h < NHEAD; ++h) {                                           \
      float4 w4 = *(const float4*)&sm.wf[h][64 * (j) + 4 * seg];                \
      acc[0][h] = fmaf(buf[0].x, w4.x, acc[0][h]);                              \
      acc[0][h] = fmaf(buf[0].y, w4.y, acc[0][h]);                              \
      acc[0][h] = fmaf(buf[0].z, w4.z, acc[0][h]);                              \
      acc[0][h] = fmaf(buf[0].w, w4.w, acc[0][h]);                              \
      acc[1][h] = fmaf(buf[1].x, w4.x, acc[1][h]);                              \
      acc[1][h] = fmaf(buf[1].y, w4.y, acc[1][h]);                              \
      acc[1][h] = fmaf(buf[1].z, w4.z, acc[1][h]);                              \
      acc[1][h] = fmaf(buf[1].w, w4.w, acc[1][h]);                              \
    }                                                                           \
  }

  const float* pcur = lanebase;
  float4 bufA[2], bufB[2];
  LDF(bufA, pcur, 0)
#pragma unroll 1
  for (int ch = 0; ch < 4; ++ch) {
    float acc[2][NHEAD];
#pragma unroll
    for (int g = 0; g < 2; ++g)
#pragma unroll
      for (int h = 0; h < NHEAD; ++h) acc[g][h] = 0.f;
    const float* pnext = pcur + 8 * rstride;
    LDF(bufB, pcur, 1)  CPF(bufA, 0)
    LDF(bufA, pcur, 2)  CPF(bufB, 1)
    LDF(bufB, pcur, 3)  CPF(bufA, 2)
    LDF(bufA, pcur, 4)  CPF(bufB, 3)
    LDF(bufB, pcur, 5)  CPF(bufA, 4)
    if (ch < 3) LDF(bufA, pnext, 0)
    CPF(bufB, 5)
#pragma unroll
    for (int g = 0; g < 2; ++g) {
      const int n = wv * 32 + ch * 8 + g * 4 + rowi;
#pragma unroll
      for (int h = 0; h < NHEAD; ++h) {
        float s = acc[g][h];
        s += __shfl_xor(s, 8);
        s += __shfl_xor(s, 4);
        s += __shfl_xor(s, 2);
        s += __shfl_xor(s, 1);
        if (seg == 0) sm.attn[h][n] = s + sm.cb[h];
      }
    }
    pcur = pnext;
  }
  __syncthreads();

  if (wv < 6) {
#pragma unroll
    for (int jh = 0; jh < 2; ++jh) {
      const int h = wv * 2 + jh;
      float v0 = sm.attn[h][lane];
      float v1 = sm.attn[h][lane + 64];
      float v2 = sm.attn[h][lane + 128];
      float v3 = sm.attn[h][lane + 192];
      float mx = fmaxf(fmaxf(v0, v1), fmaxf(v2, v3));
#pragma unroll
      for (int m = 32; m; m >>= 1) mx = fmaxf(mx, __shfl_xor(mx, m));
      float s = __expf(v0 - mx) + __expf(v1 - mx) + __expf(v2 - mx) + __expf(v3 - mx);
#pragma unroll
      for (int m = 32; m; m >>= 1) s += __shfl_xor(s, m);
      if (lane == 0) { sm.smax[h] = mx; sm.sinv[h] = 1.0f / s; }
    }
  }
  __syncthreads();

  if (t < NN) {
    float o[NHEAD];
#pragma unroll
    for (int h = 0; h < NHEAD; ++h)
      o[h] = __expf(sm.attn[h][t] - sm.smax[h]) * sm.sinv[h];
    float* ob = out + ((size_t)(b * NN + t) * LL + l) * NHEAD;
    ((float4*)ob)[0] = make_float4(o[0], o[1], o[2],  o[3]);
    ((float4*)ob)[1] = make_float4(o[4], o[5], o[6],  o[7]);
    ((float4*)ob)[2] = make_float4(o[8], o[9], o[10], o[11]);
  }
}

extern "C" void kernel_launch(void* const* d_in, const int* in_sizes, int n_in,
                              void* d_out, int out_size, void* d_ws, size_t ws_size,
                              hipStream_t stream) {
  const float* msa = (const float*)d_in[0];
  const float* Wq  = (const float*)d_in[1];
  const float* bq  = (const float*)d_in[2];
  const float* Wk  = (const float*)d_in[3];
  const float* bk  = (const float*)d_in[4];
  float* out = (float*)d_out;

  if (ws_size >= WS_BYTES) {
    float* ws     = (float*)d_ws;
    float* wf_ws  = ws + WF_OFF;
    float* q_ws   = ws + Q_OFF;
    float* cb_ws  = ws + CB_OFF;
    float* log_ws = ws + LOG_OFF;
    seqw_a1<<<dim3(NBL / 3), dim3(256), 0, stream>>>(msa, Wq, bq, bk, q_ws, cb_ws);
    seqw_a2<<<dim3(NHEAD * (NBL / 16)), dim3(256), 0, stream>>>(Wk, q_ws, wf_ws);
    seqw_b<<<dim3(NBL * 4), dim3(256), 0, stream>>>(msa, wf_ws, cb_ws, log_ws);
    seqw_c<<<dim3(NBL), dim3(256), 0, stream>>>(log_ws, out);
  } else {
    seqw_fused_fb<<<dim3(NBL), dim3(512), 0, stream>>>(msa, Wq, bq, Wk, bk, out);
  }
}